// Round 1
// baseline (783.469 us; speedup 1.0000x reference)
//
#include <hip/hip_runtime.h>
#include <stdint.h>

// ---------------------------------------------------------------------------
// Attention_53790170415368 : NAG dual-SDPA attention block, MI355X / gfx950
// Pipeline: cast -> QKV GEMM (bf16 MFMA) -> rmsnorm+rope -> v-transpose ->
//           fused pos/neg flash attention -> NAG combine -> out GEMM.
// ---------------------------------------------------------------------------

typedef short s8x __attribute__((ext_vector_type(8)));   // 8 x bf16 (raw bits)
typedef float f4x __attribute__((ext_vector_type(4)));
typedef unsigned short u16;

#define NDIM   2048
#define NHEAD  16
#define NHD    128
#define NSEQ   2560
#define NSDPA  2304

__device__ __forceinline__ u16 f2bf(float f) {
  union { float f; unsigned u; } v; v.f = f;
  unsigned r = v.u + 0x7FFFu + ((v.u >> 16) & 1u);   // RNE
  return (u16)(r >> 16);
}

__device__ __forceinline__ void gload16(const void* g, void* l) {
  __builtin_amdgcn_global_load_lds(
      (const __attribute__((address_space(1))) unsigned*)g,
      (__attribute__((address_space(3))) unsigned*)l, 16, 0, 0);
}

// ---- fp32 -> bf16 cast, 8 elems/thread --------------------------------------
__global__ void k_cvt(const float* __restrict__ src, u16* __restrict__ dst, int n8) {
  int i = blockIdx.x * blockDim.x + threadIdx.x;
  if (i >= n8) return;
  const float4* s4 = (const float4*)src + (size_t)i * 2;
  float4 a = s4[0], b = s4[1];
  uint4 p;
  p.x = (unsigned)f2bf(a.x) | ((unsigned)f2bf(a.y) << 16);
  p.y = (unsigned)f2bf(a.z) | ((unsigned)f2bf(a.w) << 16);
  p.z = (unsigned)f2bf(b.x) | ((unsigned)f2bf(b.y) << 16);
  p.w = (unsigned)f2bf(b.z) | ((unsigned)f2bf(b.w) << 16);
  *(uint4*)(dst + (size_t)i * 8) = p;
}

// ---- C[M,N] f32 = A[M,K]bf16 @ B[N,K]bf16^T  (m97 structure, 128x128 tile) --
__global__ void k_gemm_bt(const u16* __restrict__ A, const u16* __restrict__ B,
                          float* __restrict__ C, int K, int ldc) {
  __shared__ __align__(16) unsigned char sm[16384];  // A tile 8K | B tile 8K
  const int bm = blockIdx.x * 128, bn = blockIdx.y * 128;
  const int lane = threadIdx.x & 63, wl = threadIdx.x >> 6;
  const int wm = wl >> 1, wn = wl & 1;
  const int g = lane >> 4, li = lane & 15;
  f4x acc[4][4] = {};
  const int nk = K >> 5;
  for (int kk = 0; kk < nk; ++kk) {
#pragma unroll
    for (int c = 0; c < 2; ++c) {
      int base = (wl * 2 + c) * 1024;
      int row = (base >> 6) + (lane >> 2);
      int colb = (lane & 3) * 16;
      gload16((const char*)A + ((size_t)(bm + row) * K + kk * 32) * 2 + colb, sm + base);
      gload16((const char*)B + ((size_t)(bn + row) * K + kk * 32) * 2 + colb, sm + 8192 + base);
    }
    __syncthreads();
    s8x a[4];
#pragma unroll
    for (int mt = 0; mt < 4; ++mt)
      a[mt] = *(const s8x*)(sm + (wm * 64 + mt * 16 + li) * 64 + g * 16);
#pragma unroll
    for (int nt = 0; nt < 4; ++nt) {
      s8x b = *(const s8x*)(sm + 8192 + (wn * 64 + nt * 16 + li) * 64 + g * 16);
#pragma unroll
      for (int mt = 0; mt < 4; ++mt)
        acc[mt][nt] = __builtin_amdgcn_mfma_f32_16x16x32_bf16(a[mt], b, acc[mt][nt], 0, 0, 0);
    }
    __syncthreads();
  }
#pragma unroll
  for (int mt = 0; mt < 4; ++mt)
#pragma unroll
    for (int nt = 0; nt < 4; ++nt)
#pragma unroll
      for (int r = 0; r < 4; ++r) {
        int row = bm + wm * 64 + mt * 16 + g * 4 + r;
        int col = bn + wn * 64 + nt * 16 + li;
        C[(size_t)row * ldc + col] = acc[mt][nt][r];
      }
}

// ---- rmsnorm + rope for q,k ; head-major bf16 out ---------------------------
__global__ void k_rmsrope(const float* __restrict__ qkv, const float* __restrict__ nqw,
                          const float* __restrict__ nkw, const float* __restrict__ fc,
                          u16* __restrict__ qh, u16* __restrict__ kh) {
  int wid = threadIdx.x >> 6, lane = threadIdx.x & 63;
  int pair = blockIdx.x * 4 + wid;          // 0 .. 40959
  int s = pair >> 4, hh = pair & 15;
  const float* qrow = qkv + (size_t)s * 6144 + hh * 128;
  float2 qv = *(const float2*)(qrow + lane * 2);
  float2 kv = *(const float2*)(qrow + 2048 + lane * 2);
  float sq = qv.x * qv.x + qv.y * qv.y;
  float sk = kv.x * kv.x + kv.y * kv.y;
#pragma unroll
  for (int m = 32; m >= 1; m >>= 1) { sq += __shfl_xor(sq, m); sk += __shfl_xor(sk, m); }
  float rq = rsqrtf(sq * (1.f / 128.f) + 1e-5f);
  float rk = rsqrtf(sk * (1.f / 128.f) + 1e-5f);
  float2 wq2 = *(const float2*)(nqw + lane * 2);
  float2 wk2 = *(const float2*)(nkw + lane * 2);
  float2 cs = *(const float2*)(fc + (size_t)s * 128 + lane * 2);
  float q0 = qv.x * rq * wq2.x, q1 = qv.y * rq * wq2.y;
  float k0 = kv.x * rk * wk2.x, k1 = kv.y * rk * wk2.y;
  unsigned qo = (unsigned)f2bf(q0 * cs.x - q1 * cs.y) | ((unsigned)f2bf(q1 * cs.x + q0 * cs.y) << 16);
  unsigned ko = (unsigned)f2bf(k0 * cs.x - k1 * cs.y) | ((unsigned)f2bf(k1 * cs.x + k0 * cs.y) << 16);
  *(unsigned*)(qh + ((size_t)hh * NSEQ + s) * 128 + lane * 2) = qo;
  *(unsigned*)(kh + ((size_t)hh * NSEQ + s) * 128 + lane * 2) = ko;
}

// ---- v -> vT[h][d][s] bf16 (LDS transpose) ----------------------------------
__global__ void k_vtrans(const float* __restrict__ qkv, u16* __restrict__ vT) {
  __shared__ u16 t[128][65];
  int s0 = blockIdx.x * 64, hh = blockIdx.y;
  int tid = threadIdx.x;
#pragma unroll
  for (int rep = 0; rep < 32; ++rep) {
    int idx = rep * 256 + tid; int sr = idx >> 7, d = idx & 127;
    t[d][sr] = f2bf(qkv[(size_t)(s0 + sr) * 6144 + 4096 + hh * 128 + d]);
  }
  __syncthreads();
#pragma unroll
  for (int rep = 0; rep < 16; ++rep) {
    int idx = rep * 256 + tid; int d = idx >> 5, sc2 = (idx & 31) * 2;
    unsigned val = (unsigned)t[d][sc2] | ((unsigned)t[d][sc2 + 1] << 16);
    *(unsigned*)(vT + ((size_t)hh * 128 + d) * NSEQ + s0 + sc2) = val;
  }
}

// ---- flash attention, pos (z=0) / neg (z=1) ---------------------------------
// Block: 256 thr (4 waves), 128 queries/WG (32/wave = 2 m-tiles). 36 key tiles of 64.
// LDS: K tile [64][128] swz @0 | vT tile [128][64] swz @16K | P A-layout @32K
__global__ void k_attn(const u16* __restrict__ qh, const u16* __restrict__ kh,
                       const u16* __restrict__ vT, float* __restrict__ xpos,
                       float* __restrict__ xneg) {
  __shared__ __align__(16) unsigned char sm[49152];
  const int lane = threadIdx.x & 63, wl = threadIdx.x >> 6;
  const int hh = blockIdx.y, mode = blockIdx.z;
  const int q0 = blockIdx.x * 128 + wl * 32;
  const int g = lane >> 4, li = lane & 15;
  const float SCALE = 0.08838834764831845f;

  s8x aq[2][4];
#pragma unroll
  for (int mt = 0; mt < 2; ++mt) {
    int ql = q0 + mt * 16 + li;
    int qp = (mode && ql >= 2048) ? ql + 256 : ql;
    const u16* base = qh + ((size_t)hh * NSEQ + qp) * 128 + g * 8;
#pragma unroll
    for (int ds = 0; ds < 4; ++ds) aq[mt][ds] = *(const s8x*)(base + ds * 32);
  }

  const f4x zf = {0.f, 0.f, 0.f, 0.f};
  f4x o[2][8];
  float mold[2][4], lsum[2][4];
#pragma unroll
  for (int mt = 0; mt < 2; ++mt) {
#pragma unroll
    for (int dt = 0; dt < 8; ++dt) o[mt][dt] = zf;
#pragma unroll
    for (int r = 0; r < 4; ++r) { mold[mt][r] = -1e30f; lsum[mt][r] = 0.f; }
  }

  for (int kt = 0; kt < 36; ++kt) {
    int kphys = kt * 64 + ((mode && kt >= 32) ? 256 : 0);
#pragma unroll
    for (int c = 0; c < 4; ++c) {
      int base = (wl * 4 + c) * 1024;
      { int row = (base >> 8) + (lane >> 4);                 // K tile: 64 rows x 256B
        int src = (li * 16) ^ ((row & 7) << 4);
        gload16((const char*)(kh + ((size_t)hh * NSEQ + kphys + row) * 128) + src, sm + base); }
      { int row = (base >> 7) + (lane >> 3);                 // vT tile: 128 rows x 128B
        int src = ((lane & 7) * 16) ^ ((row & 7) << 4);
        gload16((const char*)(vT + ((size_t)hh * 128 + row) * NSEQ + kphys) + src,
                sm + 16384 + base); }
    }
    __syncthreads();

    f4x sc[2][4];
#pragma unroll
    for (int mt = 0; mt < 2; ++mt)
#pragma unroll
      for (int nt = 0; nt < 4; ++nt) sc[mt][nt] = zf;
#pragma unroll
    for (int nt = 0; nt < 4; ++nt) {
      int row = nt * 16 + li;
      int rx = (row & 7) << 4;
#pragma unroll
      for (int ds = 0; ds < 4; ++ds) {
        s8x bk = *(const s8x*)(sm + row * 256 + ((ds * 64 + g * 16) ^ rx));
        sc[0][nt] = __builtin_amdgcn_mfma_f32_16x16x32_bf16(aq[0][ds], bk, sc[0][nt], 0, 0, 0);
        sc[1][nt] = __builtin_amdgcn_mfma_f32_16x16x32_bf16(aq[1][ds], bk, sc[1][nt], 0, 0, 0);
      }
    }

#pragma unroll
    for (int mt = 0; mt < 2; ++mt) {
#pragma unroll
      for (int nt = 0; nt < 4; ++nt)
#pragma unroll
        for (int r = 0; r < 4; ++r) sc[mt][nt][r] *= SCALE;
#pragma unroll
      for (int r = 0; r < 4; ++r) {
        float t = fmaxf(fmaxf(sc[mt][0][r], sc[mt][1][r]), fmaxf(sc[mt][2][r], sc[mt][3][r]));
#pragma unroll
        for (int msk = 8; msk >= 1; msk >>= 1) t = fmaxf(t, __shfl_xor(t, msk));
        float mn = fmaxf(mold[mt][r], t);
        float corr = __expf(mold[mt][r] - mn);
        mold[mt][r] = mn;
        float ps = 0.f;
#pragma unroll
        for (int nt = 0; nt < 4; ++nt) {
          float p = __expf(sc[mt][nt][r] - mn);
          sc[mt][nt][r] = p; ps += p;
        }
#pragma unroll
        for (int msk = 8; msk >= 1; msk >>= 1) ps += __shfl_xor(ps, msk);
        lsum[mt][r] = lsum[mt][r] * corr + ps;
#pragma unroll
        for (int dt = 0; dt < 8; ++dt) o[mt][dt][r] *= corr;
      }
      int pao = 32768 + (wl * 2 + mt) * 2048;   // P in A-layout [16 q][64 key]
#pragma unroll
      for (int nt = 0; nt < 4; ++nt) {
        int colb = (nt * 16 + li) * 2;
#pragma unroll
        for (int r = 0; r < 4; ++r) {
          int q = g * 4 + r;
          *(u16*)(sm + pao + q * 128 + (colb ^ ((q & 7) << 4))) = f2bf(sc[mt][nt][r]);
        }
      }
    }

#pragma unroll
    for (int ks = 0; ks < 2; ++ks) {
      s8x pa[2];
#pragma unroll
      for (int mt = 0; mt < 2; ++mt) {
        int pao = 32768 + (wl * 2 + mt) * 2048;
        pa[mt] = *(const s8x*)(sm + pao + li * 128 + ((ks * 64 + g * 16) ^ ((li & 7) << 4)));
      }
#pragma unroll
      for (int dt = 0; dt < 8; ++dt) {
        int row = dt * 16 + li;
        s8x bv = *(const s8x*)(sm + 16384 + row * 128 + ((ks * 64 + g * 16) ^ ((row & 7) << 4)));
        o[0][dt] = __builtin_amdgcn_mfma_f32_16x16x32_bf16(pa[0], bv, o[0][dt], 0, 0, 0);
        o[1][dt] = __builtin_amdgcn_mfma_f32_16x16x32_bf16(pa[1], bv, o[1][dt], 0, 0, 0);
      }
    }
    __syncthreads();
  }

  float* out = mode ? xneg : xpos;
#pragma unroll
  for (int mt = 0; mt < 2; ++mt) {
    float inv[4];
#pragma unroll
    for (int r = 0; r < 4; ++r) inv[r] = 1.f / lsum[mt][r];
#pragma unroll
    for (int dt = 0; dt < 8; ++dt)
#pragma unroll
      for (int r = 0; r < 4; ++r) {
        int n = q0 + mt * 16 + g * 4 + r;
        int col = hh * 128 + dt * 16 + li;
        out[(size_t)n * NDIM + col] = o[mt][dt][r] * inv[r];
      }
  }
}

// ---- NAG combine + tail copy, bf16 X out ------------------------------------
__global__ void k_nag(const float* __restrict__ xp, const float* __restrict__ xn,
                      u16* __restrict__ X) {
  int n = blockIdx.x, t = threadIdx.x;
  if (n >= NSDPA) {   // rows 2304..2559 = x_neg rows 2048..2303
    const float* src = xn + (size_t)(n - 256) * NDIM + t * 8;
    float4 a = *(const float4*)src, b = *(const float4*)(src + 4);
    uint4 p;
    p.x = (unsigned)f2bf(a.x) | ((unsigned)f2bf(a.y) << 16);
    p.y = (unsigned)f2bf(a.z) | ((unsigned)f2bf(a.w) << 16);
    p.z = (unsigned)f2bf(b.x) | ((unsigned)f2bf(b.y) << 16);
    p.w = (unsigned)f2bf(b.z) | ((unsigned)f2bf(b.w) << 16);
    *(uint4*)(X + (size_t)n * NDIM + t * 8) = p;
    return;
  }
  const float* pr = xp + (size_t)n * NDIM + t * 8;
  const float* nr = xn + (size_t)n * NDIM + t * 8;
  float4 a = *(const float4*)pr, b = *(const float4*)(pr + 4);
  float4 c = *(const float4*)nr, d = *(const float4*)(nr + 4);
  float pv[8] = {a.x, a.y, a.z, a.w, b.x, b.y, b.z, b.w};
  float nv[8] = {c.x, c.y, c.z, c.w, d.x, d.y, d.z, d.w};
  float gv[8];
  float sp = 0.f, sg = 0.f;
#pragma unroll
  for (int i = 0; i < 8; ++i) {
    float gq = 5.f * pv[i] - 4.f * nv[i];
    gv[i] = gq; sp += fabsf(pv[i]); sg += fabsf(gq);
  }
#pragma unroll
  for (int m = 32; m >= 1; m >>= 1) { sp += __shfl_xor(sp, m); sg += __shfl_xor(sg, m); }
  __shared__ float red[2][4];
  int wid = t >> 6, lane = t & 63;
  if (lane == 0) { red[0][wid] = sp; red[1][wid] = sg; }
  __syncthreads();
  float np_ = red[0][0] + red[0][1] + red[0][2] + red[0][3];
  float ng_ = red[1][0] + red[1][1] + red[1][2] + red[1][3];
  float ratio = ng_ / np_;
  if (isnan(ratio)) ratio = 10.f;
  float factor = np_ * 2.5f / (ng_ + 1e-7f);
  float mul = (ratio > 2.5f) ? factor : 1.f;
  uint4 p;
  u16 ob[8];
#pragma unroll
  for (int i = 0; i < 8; ++i) ob[i] = f2bf(gv[i] * mul * 0.25f + pv[i] * 0.75f);
  p.x = (unsigned)ob[0] | ((unsigned)ob[1] << 16);
  p.y = (unsigned)ob[2] | ((unsigned)ob[3] << 16);
  p.z = (unsigned)ob[4] | ((unsigned)ob[5] << 16);
  p.w = (unsigned)ob[6] | ((unsigned)ob[7] << 16);
  *(uint4*)(X + (size_t)n * NDIM + t * 8) = p;
}

// ---------------------------------------------------------------------------
extern "C" void kernel_launch(void* const* d_in, const int* in_sizes, int n_in,
                              void* d_out, int out_size, void* d_ws, size_t ws_size,
                              hipStream_t stream) {
  const float* h   = (const float*)d_in[0];
  const float* wq  = (const float*)d_in[1];
  const float* wk  = (const float*)d_in[2];
  const float* wv  = (const float*)d_in[3];
  const float* wo  = (const float*)d_in[4];
  const float* nqw = (const float*)d_in[5];
  const float* nkw = (const float*)d_in[6];
  const float* fc  = (const float*)d_in[7];
  (void)in_sizes; (void)n_in; (void)out_size; (void)ws_size;

  char* ws = (char*)d_ws;
  u16*   wB   = (u16*)ws;                                   // 4 * 2048*2048 bf16 (33.55 MB)
  u16*   hB   = (u16*)(ws + 33554432);                      // 2560*2048 bf16 (10.49 MB); later X
  float* qkv  = (float*)(ws + 44040192);                    // 2560*6144 f32 (62.91 MB)
  u16*   qh   = (u16*)(ws + 106954752);                     // 16*2560*128 bf16
  u16*   kh   = qh + (size_t)16 * 2560 * 128;
  u16*   vT   = kh + (size_t)16 * 2560 * 128;
  float* xpos = qkv;                                        // alias (qkv dead after rmsrope/vtrans)
  float* xneg = xpos + (size_t)NSDPA * NDIM;
  u16*   X    = hB;                                         // alias (hB dead after GEMM1)

  k_cvt<<<2560, 256, 0, stream>>>(h, hB, 655360);
  k_cvt<<<2048, 256, 0, stream>>>(wq, wB, 524288);
  k_cvt<<<2048, 256, 0, stream>>>(wk, wB + 4194304, 524288);
  k_cvt<<<2048, 256, 0, stream>>>(wv, wB + 8388608, 524288);
  k_cvt<<<2048, 256, 0, stream>>>(wo, wB + 12582912, 524288);

  k_gemm_bt<<<dim3(20, 48), 256, 0, stream>>>(hB, wB, qkv, 2048, 6144);
  k_rmsrope<<<10240, 256, 0, stream>>>(qkv, nqw, nkw, fc, qh, kh);
  k_vtrans<<<dim3(40, 16), 256, 0, stream>>>(qkv, vT);
  k_attn<<<dim3(18, 16, 2), 256, 0, stream>>>(qh, kh, vT, xpos, xneg);
  k_nag<<<2560, 256, 0, stream>>>(xpos, xneg, X);
  k_gemm_bt<<<dim3(20, 16), 256, 0, stream>>>(X, wB + 12582912, (float*)d_out, 2048, 2048);
}

// Round 2
// 362.532 us; speedup vs baseline: 2.1611x; 2.1611x over previous
//
#include <hip/hip_runtime.h>
#include <stdint.h>

// ---------------------------------------------------------------------------
// Attention_53790170415368 : NAG dual-SDPA attention block, MI355X / gfx950
// R2: __launch_bounds__ (kill 64-VGPR spill cap), XCD-clustered head swizzle,
//     pos/neg mode fusion (shared 32-tile prefix + forked softmax state).
// ---------------------------------------------------------------------------

typedef short s8x __attribute__((ext_vector_type(8)));   // 8 x bf16 (raw bits)
typedef float f4x __attribute__((ext_vector_type(4)));
typedef unsigned short u16;

#define NDIM   2048
#define NHEAD  16
#define NHD    128
#define NSEQ   2560
#define NSDPA  2304

__device__ __forceinline__ u16 f2bf(float f) {
  union { float f; unsigned u; } v; v.f = f;
  unsigned r = v.u + 0x7FFFu + ((v.u >> 16) & 1u);   // RNE
  return (u16)(r >> 16);
}

__device__ __forceinline__ void gload16(const void* g, void* l) {
  __builtin_amdgcn_global_load_lds(
      (const __attribute__((address_space(1))) unsigned*)g,
      (__attribute__((address_space(3))) unsigned*)l, 16, 0, 0);
}

// ---- fp32 -> bf16 cast, 8 elems/thread --------------------------------------
__global__ void k_cvt(const float* __restrict__ src, u16* __restrict__ dst, int n8) {
  int i = blockIdx.x * blockDim.x + threadIdx.x;
  if (i >= n8) return;
  const float4* s4 = (const float4*)src + (size_t)i * 2;
  float4 a = s4[0], b = s4[1];
  uint4 p;
  p.x = (unsigned)f2bf(a.x) | ((unsigned)f2bf(a.y) << 16);
  p.y = (unsigned)f2bf(a.z) | ((unsigned)f2bf(a.w) << 16);
  p.z = (unsigned)f2bf(b.x) | ((unsigned)f2bf(b.y) << 16);
  p.w = (unsigned)f2bf(b.z) | ((unsigned)f2bf(b.w) << 16);
  *(uint4*)(dst + (size_t)i * 8) = p;
}

// ---- C[M,N] f32 = A[M,K]bf16 @ B[N,K]bf16^T  (m97 structure, 128x128 tile) --
__global__ __launch_bounds__(256, 2)
void k_gemm_bt(const u16* __restrict__ A, const u16* __restrict__ B,
               float* __restrict__ C, int K, int ldc) {
  __shared__ __align__(16) unsigned char sm[16384];  // A tile 8K | B tile 8K
  const int bm = blockIdx.x * 128, bn = blockIdx.y * 128;
  const int lane = threadIdx.x & 63, wl = threadIdx.x >> 6;
  const int wm = wl >> 1, wn = wl & 1;
  const int g = lane >> 4, li = lane & 15;
  f4x acc[4][4] = {};
  const int nk = K >> 5;
  for (int kk = 0; kk < nk; ++kk) {
#pragma unroll
    for (int c = 0; c < 2; ++c) {
      int base = (wl * 2 + c) * 1024;
      int row = (base >> 6) + (lane >> 2);
      int colb = (lane & 3) * 16;
      gload16((const char*)A + ((size_t)(bm + row) * K + kk * 32) * 2 + colb, sm + base);
      gload16((const char*)B + ((size_t)(bn + row) * K + kk * 32) * 2 + colb, sm + 8192 + base);
    }
    __syncthreads();
    s8x a[4];
#pragma unroll
    for (int mt = 0; mt < 4; ++mt)
      a[mt] = *(const s8x*)(sm + (wm * 64 + mt * 16 + li) * 64 + g * 16);
#pragma unroll
    for (int nt = 0; nt < 4; ++nt) {
      s8x b = *(const s8x*)(sm + 8192 + (wn * 64 + nt * 16 + li) * 64 + g * 16);
#pragma unroll
      for (int mt = 0; mt < 4; ++mt)
        acc[mt][nt] = __builtin_amdgcn_mfma_f32_16x16x32_bf16(a[mt], b, acc[mt][nt], 0, 0, 0);
    }
    __syncthreads();
  }
#pragma unroll
  for (int mt = 0; mt < 4; ++mt)
#pragma unroll
    for (int nt = 0; nt < 4; ++nt)
#pragma unroll
      for (int r = 0; r < 4; ++r) {
        int row = bm + wm * 64 + mt * 16 + g * 4 + r;
        int col = bn + wn * 64 + nt * 16 + li;
        C[(size_t)row * ldc + col] = acc[mt][nt][r];
      }
}

// ---- rmsnorm + rope for q,k ; head-major bf16 out ---------------------------
__global__ void k_rmsrope(const float* __restrict__ qkv, const float* __restrict__ nqw,
                          const float* __restrict__ nkw, const float* __restrict__ fc,
                          u16* __restrict__ qh, u16* __restrict__ kh) {
  int wid = threadIdx.x >> 6, lane = threadIdx.x & 63;
  int pair = blockIdx.x * 4 + wid;          // 0 .. 40959
  int s = pair >> 4, hh = pair & 15;
  const float* qrow = qkv + (size_t)s * 6144 + hh * 128;
  float2 qv = *(const float2*)(qrow + lane * 2);
  float2 kv = *(const float2*)(qrow + 2048 + lane * 2);
  float sq = qv.x * qv.x + qv.y * qv.y;
  float sk = kv.x * kv.x + kv.y * kv.y;
#pragma unroll
  for (int m = 32; m >= 1; m >>= 1) { sq += __shfl_xor(sq, m); sk += __shfl_xor(sk, m); }
  float rq = rsqrtf(sq * (1.f / 128.f) + 1e-5f);
  float rk = rsqrtf(sk * (1.f / 128.f) + 1e-5f);
  float2 wq2 = *(const float2*)(nqw + lane * 2);
  float2 wk2 = *(const float2*)(nkw + lane * 2);
  float2 cs = *(const float2*)(fc + (size_t)s * 128 + lane * 2);
  float q0 = qv.x * rq * wq2.x, q1 = qv.y * rq * wq2.y;
  float k0 = kv.x * rk * wk2.x, k1 = kv.y * rk * wk2.y;
  unsigned qo = (unsigned)f2bf(q0 * cs.x - q1 * cs.y) | ((unsigned)f2bf(q1 * cs.x + q0 * cs.y) << 16);
  unsigned ko = (unsigned)f2bf(k0 * cs.x - k1 * cs.y) | ((unsigned)f2bf(k1 * cs.x + k0 * cs.y) << 16);
  *(unsigned*)(qh + ((size_t)hh * NSEQ + s) * 128 + lane * 2) = qo;
  *(unsigned*)(kh + ((size_t)hh * NSEQ + s) * 128 + lane * 2) = ko;
}

// ---- v -> vT[h][d][s] bf16 (LDS transpose) ----------------------------------
__global__ void k_vtrans(const float* __restrict__ qkv, u16* __restrict__ vT) {
  __shared__ u16 t[128][65];
  int s0 = blockIdx.x * 64, hh = blockIdx.y;
  int tid = threadIdx.x;
#pragma unroll
  for (int rep = 0; rep < 32; ++rep) {
    int idx = rep * 256 + tid; int sr = idx >> 7, d = idx & 127;
    t[d][sr] = f2bf(qkv[(size_t)(s0 + sr) * 6144 + 4096 + hh * 128 + d]);
  }
  __syncthreads();
#pragma unroll
  for (int rep = 0; rep < 16; ++rep) {
    int idx = rep * 256 + tid; int d = idx >> 5, sc2 = (idx & 31) * 2;
    unsigned val = (unsigned)t[d][sc2] | ((unsigned)t[d][sc2 + 1] << 16);
    *(unsigned*)(vT + ((size_t)hh * 128 + d) * NSEQ + s0 + sc2) = val;
  }
}

// ---- flash attention helpers ------------------------------------------------
__device__ __forceinline__ void stage_kv(const u16* __restrict__ khh,
                                         const u16* __restrict__ vTh,
                                         int kphys, unsigned char* sm,
                                         int lane, int wl) {
#pragma unroll
  for (int c = 0; c < 4; ++c) {
    int base = (wl * 4 + c) * 1024;
    { int row = (base >> 8) + (lane >> 4);                 // K tile: 64 rows x 256B
      int src = ((lane & 15) * 16) ^ ((row & 7) << 4);
      gload16((const char*)(khh + (size_t)(kphys + row) * 128) + src, sm + base); }
    { int row = (base >> 7) + (lane >> 3);                 // vT tile: 128 rows x 128B
      int src = ((lane & 7) * 16) ^ ((row & 7) << 4);
      gload16((const char*)(vTh + (size_t)row * NSEQ + kphys) + src, sm + 16384 + base); }
  }
}

__device__ __forceinline__ void tile_compute(unsigned char* sm, const s8x (&aq)[2][4],
                                             int wl, int g, int li,
                                             f4x (&o)[2][8], float (&mold)[2][4],
                                             float (&lsum)[2][4]) {
  const float SCALE = 0.08838834764831845f;
  const f4x zf = {0.f, 0.f, 0.f, 0.f};
  f4x sc[2][4];
#pragma unroll
  for (int mt = 0; mt < 2; ++mt)
#pragma unroll
    for (int nt = 0; nt < 4; ++nt) sc[mt][nt] = zf;
#pragma unroll
  for (int nt = 0; nt < 4; ++nt) {
    int row = nt * 16 + li;
    int rx = (row & 7) << 4;
#pragma unroll
    for (int ds = 0; ds < 4; ++ds) {
      s8x bk = *(const s8x*)(sm + row * 256 + ((ds * 64 + g * 16) ^ rx));
      sc[0][nt] = __builtin_amdgcn_mfma_f32_16x16x32_bf16(aq[0][ds], bk, sc[0][nt], 0, 0, 0);
      sc[1][nt] = __builtin_amdgcn_mfma_f32_16x16x32_bf16(aq[1][ds], bk, sc[1][nt], 0, 0, 0);
    }
  }
#pragma unroll
  for (int mt = 0; mt < 2; ++mt) {
#pragma unroll
    for (int nt = 0; nt < 4; ++nt)
#pragma unroll
      for (int r = 0; r < 4; ++r) sc[mt][nt][r] *= SCALE;
#pragma unroll
    for (int r = 0; r < 4; ++r) {
      float t = fmaxf(fmaxf(sc[mt][0][r], sc[mt][1][r]), fmaxf(sc[mt][2][r], sc[mt][3][r]));
#pragma unroll
      for (int msk = 8; msk >= 1; msk >>= 1) t = fmaxf(t, __shfl_xor(t, msk));
      float mn = fmaxf(mold[mt][r], t);
      float corr = __expf(mold[mt][r] - mn);
      mold[mt][r] = mn;
      float ps = 0.f;
#pragma unroll
      for (int nt = 0; nt < 4; ++nt) {
        float p = __expf(sc[mt][nt][r] - mn);
        sc[mt][nt][r] = p; ps += p;
      }
#pragma unroll
      for (int msk = 8; msk >= 1; msk >>= 1) ps += __shfl_xor(ps, msk);
      lsum[mt][r] = lsum[mt][r] * corr + ps;
#pragma unroll
      for (int dt = 0; dt < 8; ++dt) o[mt][dt][r] *= corr;
    }
    int pao = 32768 + (wl * 2 + mt) * 2048;   // P in A-layout [16 q][64 key]
#pragma unroll
    for (int nt = 0; nt < 4; ++nt) {
      int colb = (nt * 16 + li) * 2;
#pragma unroll
      for (int r = 0; r < 4; ++r) {
        int q = g * 4 + r;
        *(u16*)(sm + pao + q * 128 + (colb ^ ((q & 7) << 4))) = f2bf(sc[mt][nt][r]);
      }
    }
  }
#pragma unroll
  for (int ks = 0; ks < 2; ++ks) {
    s8x pa[2];
#pragma unroll
    for (int mt = 0; mt < 2; ++mt) {
      int pao = 32768 + (wl * 2 + mt) * 2048;
      pa[mt] = *(const s8x*)(sm + pao + li * 128 + ((ks * 64 + g * 16) ^ ((li & 7) << 4)));
    }
#pragma unroll
    for (int dt = 0; dt < 8; ++dt) {
      int row = dt * 16 + li;
      s8x bv = *(const s8x*)(sm + 16384 + row * 128 + ((ks * 64 + g * 16) ^ ((row & 7) << 4)));
      o[0][dt] = __builtin_amdgcn_mfma_f32_16x16x32_bf16(pa[0], bv, o[0][dt], 0, 0, 0);
      o[1][dt] = __builtin_amdgcn_mfma_f32_16x16x32_bf16(pa[1], bv, o[1][dt], 0, 0, 0);
    }
  }
}

__device__ __forceinline__ void epilogue(float* __restrict__ out, int q0, int hh,
                                         int g, int li, const f4x (&o)[2][8],
                                         const float (&lsum)[2][4]) {
#pragma unroll
  for (int mt = 0; mt < 2; ++mt) {
    float inv[4];
#pragma unroll
    for (int r = 0; r < 4; ++r) inv[r] = 1.f / lsum[mt][r];
#pragma unroll
    for (int dt = 0; dt < 8; ++dt)
#pragma unroll
      for (int r = 0; r < 4; ++r) {
        int n = q0 + mt * 16 + g * 4 + r;
        int col = hh * 128 + dt * 16 + li;
        out[(size_t)n * NDIM + col] = o[mt][dt][r] * inv[r];
      }
  }
}

// ---- fused pos/neg flash attention ------------------------------------------
// 320 blocks, 256 thr (4 waves), 128 q-rows/WG. XCD x owns heads {2x, 2x+1}.
// Units u: 0..15 = shared q-block (pos/neg fused: 32 shared tiles + 4+4 tails);
//          16..19 = divergent q-blocks 16,17 x mode (36 tiles each).
// LDS: K tile [64][128]swz @0 | vT tile [128][64]swz @16K | P A-layout @32K
__global__ __launch_bounds__(256, 2)
void k_attn(const u16* __restrict__ qh, const u16* __restrict__ kh,
            const u16* __restrict__ vT, float* __restrict__ xpos,
            float* __restrict__ xneg) {
  __shared__ __align__(16) unsigned char sm[49152];
  const int lane = threadIdx.x & 63, wl = threadIdx.x >> 6;
  const int g = lane >> 4, li = lane & 15;

  const int s = blockIdx.x;            // 0..319
  const int xcd = s & 7, j = s >> 3;   // consecutive ids round-robin XCDs
  const int hh = 2 * xcd + (j & 1);
  const int u = j >> 1;                // 0..19
  const bool shared_blk = (u < 16);
  const int qb = shared_blk ? u : (16 + ((u - 16) >> 1));
  const int mode = shared_blk ? 0 : ((u - 16) & 1);
  const int q0 = qb * 128 + wl * 32;

  const u16* khh = kh + (size_t)hh * NSEQ * 128;
  const u16* vTh = vT + (size_t)hh * 128 * NSEQ;

  s8x aq[2][4];
#pragma unroll
  for (int mt = 0; mt < 2; ++mt) {
    int ql = q0 + mt * 16 + li;
    int qp = (mode && ql >= 2048) ? ql + 256 : ql;
    const u16* base = qh + ((size_t)hh * NSEQ + qp) * 128 + g * 8;
#pragma unroll
    for (int ds = 0; ds < 4; ++ds) aq[mt][ds] = *(const s8x*)(base + ds * 32);
  }

  const f4x zf = {0.f, 0.f, 0.f, 0.f};
  f4x o1[2][8];
  float m1[2][4], l1[2][4];
#pragma unroll
  for (int mt = 0; mt < 2; ++mt) {
#pragma unroll
    for (int dt = 0; dt < 8; ++dt) o1[mt][dt] = zf;
#pragma unroll
    for (int r = 0; r < 4; ++r) { m1[mt][r] = -1e30f; l1[mt][r] = 0.f; }
  }

  const int n1 = shared_blk ? 32 : 36;
  for (int t = 0; t < n1; ++t) {
    int kphys = (mode && t >= 32) ? 2304 + (t - 32) * 64 : t * 64;
    stage_kv(khh, vTh, kphys, sm, lane, wl);
    __syncthreads();
    tile_compute(sm, aq, wl, g, li, o1, m1, l1);
    __syncthreads();
  }

  if (shared_blk) {
    f4x o2[2][8];
    float m2[2][4], l2[2][4];
#pragma unroll
    for (int mt = 0; mt < 2; ++mt) {
#pragma unroll
      for (int dt = 0; dt < 8; ++dt) o2[mt][dt] = o1[mt][dt];
#pragma unroll
      for (int r = 0; r < 4; ++r) { m2[mt][r] = m1[mt][r]; l2[mt][r] = l1[mt][r]; }
    }
    for (int t = 0; t < 4; ++t) {              // pos tail: phys 2048..2303
      stage_kv(khh, vTh, 2048 + t * 64, sm, lane, wl);
      __syncthreads();
      tile_compute(sm, aq, wl, g, li, o1, m1, l1);
      __syncthreads();
    }
    for (int t = 0; t < 4; ++t) {              // neg tail: phys 2304..2559
      stage_kv(khh, vTh, 2304 + t * 64, sm, lane, wl);
      __syncthreads();
      tile_compute(sm, aq, wl, g, li, o2, m2, l2);
      __syncthreads();
    }
    epilogue(xpos, q0, hh, g, li, o1, l1);
    epilogue(xneg, q0, hh, g, li, o2, l2);
  } else {
    epilogue(mode ? xneg : xpos, q0, hh, g, li, o1, l1);
  }
}

// ---- NAG combine + tail copy, bf16 X out ------------------------------------
__global__ void k_nag(const float* __restrict__ xp, const float* __restrict__ xn,
                      u16* __restrict__ X) {
  int n = blockIdx.x, t = threadIdx.x;
  if (n >= NSDPA) {   // rows 2304..2559 = x_neg rows 2048..2303
    const float* src = xn + (size_t)(n - 256) * NDIM + t * 8;
    float4 a = *(const float4*)src, b = *(const float4*)(src + 4);
    uint4 p;
    p.x = (unsigned)f2bf(a.x) | ((unsigned)f2bf(a.y) << 16);
    p.y = (unsigned)f2bf(a.z) | ((unsigned)f2bf(a.w) << 16);
    p.z = (unsigned)f2bf(b.x) | ((unsigned)f2bf(b.y) << 16);
    p.w = (unsigned)f2bf(b.z) | ((unsigned)f2bf(b.w) << 16);
    *(uint4*)(X + (size_t)n * NDIM + t * 8) = p;
    return;
  }
  const float* pr = xp + (size_t)n * NDIM + t * 8;
  const float* nr = xn + (size_t)n * NDIM + t * 8;
  float4 a = *(const float4*)pr, b = *(const float4*)(pr + 4);
  float4 c = *(const float4*)nr, d = *(const float4*)(nr + 4);
  float pv[8] = {a.x, a.y, a.z, a.w, b.x, b.y, b.z, b.w};
  float nv[8] = {c.x, c.y, c.z, c.w, d.x, d.y, d.z, d.w};
  float gv[8];
  float sp = 0.f, sg = 0.f;
#pragma unroll
  for (int i = 0; i < 8; ++i) {
    float gq = 5.f * pv[i] - 4.f * nv[i];
    gv[i] = gq; sp += fabsf(pv[i]); sg += fabsf(gq);
  }
#pragma unroll
  for (int m = 32; m >= 1; m >>= 1) { sp += __shfl_xor(sp, m); sg += __shfl_xor(sg, m); }
  __shared__ float red[2][4];
  int wid = t >> 6, lane = t & 63;
  if (lane == 0) { red[0][wid] = sp; red[1][wid] = sg; }
  __syncthreads();
  float np_ = red[0][0] + red[0][1] + red[0][2] + red[0][3];
  float ng_ = red[1][0] + red[1][1] + red[1][2] + red[1][3];
  float ratio = ng_ / np_;
  if (isnan(ratio)) ratio = 10.f;
  float factor = np_ * 2.5f / (ng_ + 1e-7f);
  float mul = (ratio > 2.5f) ? factor : 1.f;
  uint4 p;
  u16 ob[8];
#pragma unroll
  for (int i = 0; i < 8; ++i) ob[i] = f2bf(gv[i] * mul * 0.25f + pv[i] * 0.75f);
  p.x = (unsigned)ob[0] | ((unsigned)ob[1] << 16);
  p.y = (unsigned)ob[2] | ((unsigned)ob[3] << 16);
  p.z = (unsigned)ob[4] | ((unsigned)ob[5] << 16);
  p.w = (unsigned)ob[6] | ((unsigned)ob[7] << 16);
  *(uint4*)(X + (size_t)n * NDIM + t * 8) = p;
}

// ---------------------------------------------------------------------------
extern "C" void kernel_launch(void* const* d_in, const int* in_sizes, int n_in,
                              void* d_out, int out_size, void* d_ws, size_t ws_size,
                              hipStream_t stream) {
  const float* h   = (const float*)d_in[0];
  const float* wq  = (const float*)d_in[1];
  const float* wk  = (const float*)d_in[2];
  const float* wv  = (const float*)d_in[3];
  const float* wo  = (const float*)d_in[4];
  const float* nqw = (const float*)d_in[5];
  const float* nkw = (const float*)d_in[6];
  const float* fc  = (const float*)d_in[7];
  (void)in_sizes; (void)n_in; (void)out_size; (void)ws_size;

  char* ws = (char*)d_ws;
  u16*   wB   = (u16*)ws;                                   // 4 * 2048*2048 bf16 (33.55 MB)
  u16*   hB   = (u16*)(ws + 33554432);                      // 2560*2048 bf16 (10.49 MB); later X
  float* qkv  = (float*)(ws + 44040192);                    // 2560*6144 f32 (62.91 MB)
  u16*   qh   = (u16*)(ws + 106954752);                     // 16*2560*128 bf16
  u16*   kh   = qh + (size_t)16 * 2560 * 128;
  u16*   vT   = kh + (size_t)16 * 2560 * 128;
  float* xpos = qkv;                                        // alias (qkv dead after rmsrope/vtrans)
  float* xneg = xpos + (size_t)NSDPA * NDIM;
  u16*   X    = hB;                                         // alias (hB dead after GEMM1)

  k_cvt<<<2560, 256, 0, stream>>>(h, hB, 655360);
  k_cvt<<<2048, 256, 0, stream>>>(wq, wB, 524288);
  k_cvt<<<2048, 256, 0, stream>>>(wk, wB + 4194304, 524288);
  k_cvt<<<2048, 256, 0, stream>>>(wv, wB + 8388608, 524288);
  k_cvt<<<2048, 256, 0, stream>>>(wo, wB + 12582912, 524288);

  k_gemm_bt<<<dim3(20, 48), 256, 0, stream>>>(hB, wB, qkv, 2048, 6144);
  k_rmsrope<<<10240, 256, 0, stream>>>(qkv, nqw, nkw, fc, qh, kh);
  k_vtrans<<<dim3(40, 16), 256, 0, stream>>>(qkv, vT);
  k_attn<<<320, 256, 0, stream>>>(qh, kh, vT, xpos, xneg);
  k_nag<<<2560, 256, 0, stream>>>(xpos, xneg, X);
  k_gemm_bt<<<dim3(20, 16), 256, 0, stream>>>(X, wB + 12582912, (float*)d_out, 2048, 2048);
}

// Round 3
// 311.663 us; speedup vs baseline: 2.5138x; 1.1632x over previous
//
#include <hip/hip_runtime.h>
#include <stdint.h>

// ---------------------------------------------------------------------------
// Attention_53790170415368 : NAG dual-SDPA attention block, MI355X / gfx950
// R3: 640-block attention (64 q/WG, 3 blocks/CU), defer-max softmax,
//     folded exp scale, setprio on MFMA clusters, fused weight casts.
// ---------------------------------------------------------------------------

typedef short s8x __attribute__((ext_vector_type(8)));   // 8 x bf16 (raw bits)
typedef float f4x __attribute__((ext_vector_type(4)));
typedef unsigned short u16;

#define NDIM   2048
#define NHEAD  16
#define NHD    128
#define NSEQ   2560
#define NSDPA  2304

__device__ __forceinline__ u16 f2bf(float f) {
  union { float f; unsigned u; } v; v.f = f;
  unsigned r = v.u + 0x7FFFu + ((v.u >> 16) & 1u);   // RNE
  return (u16)(r >> 16);
}

__device__ __forceinline__ void gload16(const void* g, void* l) {
  __builtin_amdgcn_global_load_lds(
      (const __attribute__((address_space(1))) unsigned*)g,
      (__attribute__((address_space(3))) unsigned*)l, 16, 0, 0);
}

// ---- fp32 -> bf16 cast, 8 elems/thread --------------------------------------
__global__ void k_cvt(const float* __restrict__ src, u16* __restrict__ dst, int n8) {
  int i = blockIdx.x * blockDim.x + threadIdx.x;
  if (i >= n8) return;
  const float4* s4 = (const float4*)src + (size_t)i * 2;
  float4 a = s4[0], b = s4[1];
  uint4 p;
  p.x = (unsigned)f2bf(a.x) | ((unsigned)f2bf(a.y) << 16);
  p.y = (unsigned)f2bf(a.z) | ((unsigned)f2bf(a.w) << 16);
  p.z = (unsigned)f2bf(b.x) | ((unsigned)f2bf(b.y) << 16);
  p.w = (unsigned)f2bf(b.z) | ((unsigned)f2bf(b.w) << 16);
  *(uint4*)(dst + (size_t)i * 8) = p;
}

// ---- 4 weight matrices in one launch (blockIdx.y selects) -------------------
__global__ void k_cvt4(const float* __restrict__ w0, const float* __restrict__ w1,
                       const float* __restrict__ w2, const float* __restrict__ w3,
                       u16* __restrict__ dst) {
  int i = blockIdx.x * blockDim.x + threadIdx.x;           // 0 .. 524287
  int m = blockIdx.y;
  const float* src = (m == 0) ? w0 : (m == 1) ? w1 : (m == 2) ? w2 : w3;
  const float4* s4 = (const float4*)src + (size_t)i * 2;
  float4 a = s4[0], b = s4[1];
  uint4 p;
  p.x = (unsigned)f2bf(a.x) | ((unsigned)f2bf(a.y) << 16);
  p.y = (unsigned)f2bf(a.z) | ((unsigned)f2bf(a.w) << 16);
  p.z = (unsigned)f2bf(b.x) | ((unsigned)f2bf(b.y) << 16);
  p.w = (unsigned)f2bf(b.z) | ((unsigned)f2bf(b.w) << 16);
  *(uint4*)(dst + (size_t)m * 4194304 + (size_t)i * 8) = p;
}

// ---- C[M,N] f32 = A[M,K]bf16 @ B[N,K]bf16^T  (m97 structure, 128x128 tile) --
__global__ __launch_bounds__(256, 2)
void k_gemm_bt(const u16* __restrict__ A, const u16* __restrict__ B,
               float* __restrict__ C, int K, int ldc) {
  __shared__ __align__(16) unsigned char sm[16384];  // A tile 8K | B tile 8K
  const int bm = blockIdx.x * 128, bn = blockIdx.y * 128;
  const int lane = threadIdx.x & 63, wl = threadIdx.x >> 6;
  const int wm = wl >> 1, wn = wl & 1;
  const int g = lane >> 4, li = lane & 15;
  f4x acc[4][4] = {};
  const int nk = K >> 5;
  for (int kk = 0; kk < nk; ++kk) {
#pragma unroll
    for (int c = 0; c < 2; ++c) {
      int base = (wl * 2 + c) * 1024;
      int row = (base >> 6) + (lane >> 2);
      int colb = (lane & 3) * 16;
      gload16((const char*)A + ((size_t)(bm + row) * K + kk * 32) * 2 + colb, sm + base);
      gload16((const char*)B + ((size_t)(bn + row) * K + kk * 32) * 2 + colb, sm + 8192 + base);
    }
    __syncthreads();
    s8x a[4];
#pragma unroll
    for (int mt = 0; mt < 4; ++mt)
      a[mt] = *(const s8x*)(sm + (wm * 64 + mt * 16 + li) * 64 + g * 16);
#pragma unroll
    for (int nt = 0; nt < 4; ++nt) {
      s8x b = *(const s8x*)(sm + 8192 + (wn * 64 + nt * 16 + li) * 64 + g * 16);
#pragma unroll
      for (int mt = 0; mt < 4; ++mt)
        acc[mt][nt] = __builtin_amdgcn_mfma_f32_16x16x32_bf16(a[mt], b, acc[mt][nt], 0, 0, 0);
    }
    __syncthreads();
  }
#pragma unroll
  for (int mt = 0; mt < 4; ++mt)
#pragma unroll
    for (int nt = 0; nt < 4; ++nt)
#pragma unroll
      for (int r = 0; r < 4; ++r) {
        int row = bm + wm * 64 + mt * 16 + g * 4 + r;
        int col = bn + wn * 64 + nt * 16 + li;
        C[(size_t)row * ldc + col] = acc[mt][nt][r];
      }
}

// ---- rmsnorm + rope for q,k ; head-major bf16 out ---------------------------
__global__ void k_rmsrope(const float* __restrict__ qkv, const float* __restrict__ nqw,
                          const float* __restrict__ nkw, const float* __restrict__ fc,
                          u16* __restrict__ qh, u16* __restrict__ kh) {
  int wid = threadIdx.x >> 6, lane = threadIdx.x & 63;
  int pair = blockIdx.x * 4 + wid;          // 0 .. 40959
  int s = pair >> 4, hh = pair & 15;
  const float* qrow = qkv + (size_t)s * 6144 + hh * 128;
  float2 qv = *(const float2*)(qrow + lane * 2);
  float2 kv = *(const float2*)(qrow + 2048 + lane * 2);
  float sq = qv.x * qv.x + qv.y * qv.y;
  float sk = kv.x * kv.x + kv.y * kv.y;
#pragma unroll
  for (int m = 32; m >= 1; m >>= 1) { sq += __shfl_xor(sq, m); sk += __shfl_xor(sk, m); }
  float rq = rsqrtf(sq * (1.f / 128.f) + 1e-5f);
  float rk = rsqrtf(sk * (1.f / 128.f) + 1e-5f);
  float2 wq2 = *(const float2*)(nqw + lane * 2);
  float2 wk2 = *(const float2*)(nkw + lane * 2);
  float2 cs = *(const float2*)(fc + (size_t)s * 128 + lane * 2);
  float q0 = qv.x * rq * wq2.x, q1 = qv.y * rq * wq2.y;
  float k0 = kv.x * rk * wk2.x, k1 = kv.y * rk * wk2.y;
  unsigned qo = (unsigned)f2bf(q0 * cs.x - q1 * cs.y) | ((unsigned)f2bf(q1 * cs.x + q0 * cs.y) << 16);
  unsigned ko = (unsigned)f2bf(k0 * cs.x - k1 * cs.y) | ((unsigned)f2bf(k1 * cs.x + k0 * cs.y) << 16);
  *(unsigned*)(qh + ((size_t)hh * NSEQ + s) * 128 + lane * 2) = qo;
  *(unsigned*)(kh + ((size_t)hh * NSEQ + s) * 128 + lane * 2) = ko;
}

// ---- v -> vT[h][d][s] bf16 (LDS transpose) ----------------------------------
__global__ void k_vtrans(const float* __restrict__ qkv, u16* __restrict__ vT) {
  __shared__ u16 t[128][65];
  int s0 = blockIdx.x * 64, hh = blockIdx.y;
  int tid = threadIdx.x;
#pragma unroll
  for (int rep = 0; rep < 32; ++rep) {
    int idx = rep * 256 + tid; int sr = idx >> 7, d = idx & 127;
    t[d][sr] = f2bf(qkv[(size_t)(s0 + sr) * 6144 + 4096 + hh * 128 + d]);
  }
  __syncthreads();
#pragma unroll
  for (int rep = 0; rep < 16; ++rep) {
    int idx = rep * 256 + tid; int d = idx >> 5, sc2 = (idx & 31) * 2;
    unsigned val = (unsigned)t[d][sc2] | ((unsigned)t[d][sc2 + 1] << 16);
    *(unsigned*)(vT + ((size_t)hh * 128 + d) * NSEQ + s0 + sc2) = val;
  }
}

// ---- flash attention helpers ------------------------------------------------
// LDS: K tile [64][128]swz @0 (16K) | vT tile [128][64]swz @16K | P @32K (8K)
__device__ __forceinline__ void stage_kv(const u16* __restrict__ khh,
                                         const u16* __restrict__ vTh,
                                         int kphys, unsigned char* sm,
                                         int lane, int wl) {
#pragma unroll
  for (int c = 0; c < 4; ++c) {
    int base = (wl * 4 + c) * 1024;
    { int row = (base >> 8) + (lane >> 4);                 // K tile: 64 rows x 256B
      int src = ((lane & 15) * 16) ^ ((row & 7) << 4);
      gload16((const char*)(khh + (size_t)(kphys + row) * 128) + src, sm + base); }
    { int row = (base >> 7) + (lane >> 3);                 // vT tile: 128 rows x 128B
      int src = ((lane & 7) * 16) ^ ((row & 7) << 4);
      gload16((const char*)(vTh + (size_t)row * NSEQ + kphys) + src, sm + 16384 + base); }
  }
}

__device__ __forceinline__ void tile_compute(unsigned char* sm, const s8x (&aq)[4],
                                             int wl, int g, int li,
                                             f4x (&o)[8], float (&mold)[4],
                                             float (&lsum)[4]) {
  const float SCALE = 0.08838834764831845f;
  const float THR_RAW = 90.0f;                 // ~8 in exp-arg units
  const f4x zf = {0.f, 0.f, 0.f, 0.f};
  f4x sc[4];
#pragma unroll
  for (int nt = 0; nt < 4; ++nt) sc[nt] = zf;
  __builtin_amdgcn_s_setprio(1);
#pragma unroll
  for (int nt = 0; nt < 4; ++nt) {
    int row = nt * 16 + li;
    int rx = (row & 7) << 4;
#pragma unroll
    for (int ds = 0; ds < 4; ++ds) {
      s8x bk = *(const s8x*)(sm + row * 256 + ((ds * 64 + g * 16) ^ rx));
      sc[nt] = __builtin_amdgcn_mfma_f32_16x16x32_bf16(aq[ds], bk, sc[nt], 0, 0, 0);
    }
  }
  __builtin_amdgcn_s_setprio(0);

  float t[4];
#pragma unroll
  for (int r = 0; r < 4; ++r) {
    t[r] = fmaxf(fmaxf(sc[0][r], sc[1][r]), fmaxf(sc[2][r], sc[3][r]));
#pragma unroll
    for (int msk = 8; msk >= 1; msk >>= 1) t[r] = fmaxf(t[r], __shfl_xor(t[r], msk));
  }
  bool need = (t[0] > mold[0] + THR_RAW) || (t[1] > mold[1] + THR_RAW) ||
              (t[2] > mold[2] + THR_RAW) || (t[3] > mold[3] + THR_RAW);
  if (__any((int)need)) {                      // wave-uniform rescale (rare after warmup)
#pragma unroll
    for (int r = 0; r < 4; ++r) {
      float mn = fmaxf(mold[r], t[r]);
      float corr = __expf((mold[r] - mn) * SCALE);
      mold[r] = mn;
      lsum[r] *= corr;
#pragma unroll
      for (int dt = 0; dt < 8; ++dt) o[dt][r] *= corr;
    }
  }
  float ps[4] = {0.f, 0.f, 0.f, 0.f};
#pragma unroll
  for (int nt = 0; nt < 4; ++nt)
#pragma unroll
    for (int r = 0; r < 4; ++r) {
      float p = __expf((sc[nt][r] - mold[r]) * SCALE);
      sc[nt][r] = p; ps[r] += p;
    }
#pragma unroll
  for (int r = 0; r < 4; ++r) {
#pragma unroll
    for (int msk = 8; msk >= 1; msk >>= 1) ps[r] += __shfl_xor(ps[r], msk);
    lsum[r] += ps[r];
  }
  const int pao = 32768 + wl * 2048;           // P A-layout [16 q][64 key] swz
#pragma unroll
  for (int nt = 0; nt < 4; ++nt) {
    int colb = (nt * 16 + li) * 2;
#pragma unroll
    for (int r = 0; r < 4; ++r) {
      int q = g * 4 + r;
      *(u16*)(sm + pao + q * 128 + (colb ^ ((q & 7) << 4))) = f2bf(sc[nt][r]);
    }
  }
  __builtin_amdgcn_s_setprio(1);
#pragma unroll
  for (int ks = 0; ks < 2; ++ks) {
    s8x pa = *(const s8x*)(sm + pao + li * 128 + ((ks * 64 + g * 16) ^ ((li & 7) << 4)));
#pragma unroll
    for (int dt = 0; dt < 8; ++dt) {
      int row = dt * 16 + li;
      s8x bv = *(const s8x*)(sm + 16384 + row * 128 + ((ks * 64 + g * 16) ^ ((row & 7) << 4)));
      o[dt] = __builtin_amdgcn_mfma_f32_16x16x32_bf16(pa, bv, o[dt], 0, 0, 0);
    }
  }
  __builtin_amdgcn_s_setprio(0);
}

__device__ __forceinline__ void epilogue(float* __restrict__ out, int q0, int hh,
                                         int g, int li, const f4x (&o)[8],
                                         const float (&lsum)[4]) {
  float inv[4];
#pragma unroll
  for (int r = 0; r < 4; ++r) inv[r] = 1.f / lsum[r];
#pragma unroll
  for (int dt = 0; dt < 8; ++dt)
#pragma unroll
    for (int r = 0; r < 4; ++r) {
      int n = q0 + g * 4 + r;
      int col = hh * 128 + dt * 16 + li;
      out[(size_t)n * NDIM + col] = o[dt][r] * inv[r];
    }
}

// ---- fused pos/neg flash attention ------------------------------------------
// 640 blocks, 256 thr (4 waves), 64 q-rows/WG (16/wave). XCD x: heads {2x,2x+1}.
// j = s>>3 in 0..79: hh = 2*xcd + (j&1); u = j>>1 in 0..39:
//   u<32  -> shared q-block (pos/neg fused: 32 shared tiles + 4+4 tails)
//   u>=32 -> divergent q-blocks 32..35 x mode (36 tiles)
__global__ __launch_bounds__(256, 3)
void k_attn(const u16* __restrict__ qh, const u16* __restrict__ kh,
            const u16* __restrict__ vT, float* __restrict__ xpos,
            float* __restrict__ xneg) {
  __shared__ __align__(16) unsigned char sm[40960];
  const int lane = threadIdx.x & 63, wl = threadIdx.x >> 6;
  const int g = lane >> 4, li = lane & 15;

  const int s = blockIdx.x;            // 0..639
  const int xcd = s & 7, j = s >> 3;
  const int hh = 2 * xcd + (j & 1);
  const int u = j >> 1;                // 0..39
  const bool shared_blk = (u < 32);
  const int qb = shared_blk ? u : (32 + ((u - 32) >> 1));
  const int mode = shared_blk ? 0 : ((u - 32) & 1);
  const int q0 = qb * 64 + wl * 16;

  const u16* khh = kh + (size_t)hh * NSEQ * 128;
  const u16* vTh = vT + (size_t)hh * 128 * NSEQ;

  s8x aq[4];
  {
    int ql = q0 + li;
    int qp = (mode && ql >= 2048) ? ql + 256 : ql;
    const u16* base = qh + ((size_t)hh * NSEQ + qp) * 128 + g * 8;
#pragma unroll
    for (int ds = 0; ds < 4; ++ds) aq[ds] = *(const s8x*)(base + ds * 32);
  }

  const f4x zf = {0.f, 0.f, 0.f, 0.f};
  f4x o1[8];
  float m1[4], l1[4];
#pragma unroll
  for (int dt = 0; dt < 8; ++dt) o1[dt] = zf;
#pragma unroll
  for (int r = 0; r < 4; ++r) { m1[r] = -1e30f; l1[r] = 0.f; }

  const int n1 = shared_blk ? 32 : 36;
  for (int t = 0; t < n1; ++t) {
    int kphys = (mode && t >= 32) ? 2304 + (t - 32) * 64 : t * 64;
    stage_kv(khh, vTh, kphys, sm, lane, wl);
    __syncthreads();
    tile_compute(sm, aq, wl, g, li, o1, m1, l1);
    __syncthreads();
  }

  if (shared_blk) {
    f4x o2[8];
    float m2[4], l2[4];
#pragma unroll
    for (int dt = 0; dt < 8; ++dt) o2[dt] = o1[dt];
#pragma unroll
    for (int r = 0; r < 4; ++r) { m2[r] = m1[r]; l2[r] = l1[r]; }
    for (int t = 0; t < 4; ++t) {              // pos tail: phys 2048..2303
      stage_kv(khh, vTh, 2048 + t * 64, sm, lane, wl);
      __syncthreads();
      tile_compute(sm, aq, wl, g, li, o1, m1, l1);
      __syncthreads();
    }
    epilogue(xpos, q0, hh, g, li, o1, l1);     // free o1 before neg tail
    for (int t = 0; t < 4; ++t) {              // neg tail: phys 2304..2559
      stage_kv(khh, vTh, 2304 + t * 64, sm, lane, wl);
      __syncthreads();
      tile_compute(sm, aq, wl, g, li, o2, m2, l2);
      __syncthreads();
    }
    epilogue(xneg, q0, hh, g, li, o2, l2);
  } else {
    epilogue(mode ? xneg : xpos, q0, hh, g, li, o1, l1);
  }
}

// ---- NAG combine + tail copy, bf16 X out ------------------------------------
__global__ void k_nag(const float* __restrict__ xp, const float* __restrict__ xn,
                      u16* __restrict__ X) {
  int n = blockIdx.x, t = threadIdx.x;
  if (n >= NSDPA) {   // rows 2304..2559 = x_neg rows 2048..2303
    const float* src = xn + (size_t)(n - 256) * NDIM + t * 8;
    float4 a = *(const float4*)src, b = *(const float4*)(src + 4);
    uint4 p;
    p.x = (unsigned)f2bf(a.x) | ((unsigned)f2bf(a.y) << 16);
    p.y = (unsigned)f2bf(a.z) | ((unsigned)f2bf(a.w) << 16);
    p.z = (unsigned)f2bf(b.x) | ((unsigned)f2bf(b.y) << 16);
    p.w = (unsigned)f2bf(b.z) | ((unsigned)f2bf(b.w) << 16);
    *(uint4*)(X + (size_t)n * NDIM + t * 8) = p;
    return;
  }
  const float* pr = xp + (size_t)n * NDIM + t * 8;
  const float* nr = xn + (size_t)n * NDIM + t * 8;
  float4 a = *(const float4*)pr, b = *(const float4*)(pr + 4);
  float4 c = *(const float4*)nr, d = *(const float4*)(nr + 4);
  float pv[8] = {a.x, a.y, a.z, a.w, b.x, b.y, b.z, b.w};
  float nv[8] = {c.x, c.y, c.z, c.w, d.x, d.y, d.z, d.w};
  float gv[8];
  float sp = 0.f, sg = 0.f;
#pragma unroll
  for (int i = 0; i < 8; ++i) {
    float gq = 5.f * pv[i] - 4.f * nv[i];
    gv[i] = gq; sp += fabsf(pv[i]); sg += fabsf(gq);
  }
#pragma unroll
  for (int m = 32; m >= 1; m >>= 1) { sp += __shfl_xor(sp, m); sg += __shfl_xor(sg, m); }
  __shared__ float red[2][4];
  int wid = t >> 6, lane = t & 63;
  if (lane == 0) { red[0][wid] = sp; red[1][wid] = sg; }
  __syncthreads();
  float np_ = red[0][0] + red[0][1] + red[0][2] + red[0][3];
  float ng_ = red[1][0] + red[1][1] + red[1][2] + red[1][3];
  float ratio = ng_ / np_;
  if (isnan(ratio)) ratio = 10.f;
  float factor = np_ * 2.5f / (ng_ + 1e-7f);
  float mul = (ratio > 2.5f) ? factor : 1.f;
  uint4 p;
  u16 ob[8];
#pragma unroll
  for (int i = 0; i < 8; ++i) ob[i] = f2bf(gv[i] * mul * 0.25f + pv[i] * 0.75f);
  p.x = (unsigned)ob[0] | ((unsigned)ob[1] << 16);
  p.y = (unsigned)ob[2] | ((unsigned)ob[3] << 16);
  p.z = (unsigned)ob[4] | ((unsigned)ob[5] << 16);
  p.w = (unsigned)ob[6] | ((unsigned)ob[7] << 16);
  *(uint4*)(X + (size_t)n * NDIM + t * 8) = p;
}

// ---------------------------------------------------------------------------
extern "C" void kernel_launch(void* const* d_in, const int* in_sizes, int n_in,
                              void* d_out, int out_size, void* d_ws, size_t ws_size,
                              hipStream_t stream) {
  const float* h   = (const float*)d_in[0];
  const float* wq  = (const float*)d_in[1];
  const float* wk  = (const float*)d_in[2];
  const float* wv  = (const float*)d_in[3];
  const float* wo  = (const float*)d_in[4];
  const float* nqw = (const float*)d_in[5];
  const float* nkw = (const float*)d_in[6];
  const float* fc  = (const float*)d_in[7];
  (void)in_sizes; (void)n_in; (void)out_size; (void)ws_size;

  char* ws = (char*)d_ws;
  u16*   wB   = (u16*)ws;                                   // 4 * 2048*2048 bf16 (33.55 MB)
  u16*   hB   = (u16*)(ws + 33554432);                      // 2560*2048 bf16; later X
  float* qkv  = (float*)(ws + 44040192);                    // 2560*6144 f32 (62.91 MB)
  u16*   qh   = (u16*)(ws + 106954752);                     // 16*2560*128 bf16
  u16*   kh   = qh + (size_t)16 * 2560 * 128;
  u16*   vT   = kh + (size_t)16 * 2560 * 128;
  float* xpos = qkv;                                        // alias (qkv dead after rmsrope/vtrans)
  float* xneg = xpos + (size_t)NSDPA * NDIM;
  u16*   X    = hB;                                         // alias (hB dead after GEMM1)

  k_cvt<<<2560, 256, 0, stream>>>(h, hB, 655360);
  k_cvt4<<<dim3(2048, 4), 256, 0, stream>>>(wq, wk, wv, wo, wB);

  k_gemm_bt<<<dim3(20, 48), 256, 0, stream>>>(hB, wB, qkv, 2048, 6144);
  k_rmsrope<<<10240, 256, 0, stream>>>(qkv, nqw, nkw, fc, qh, kh);
  k_vtrans<<<dim3(40, 16), 256, 0, stream>>>(qkv, vT);
  k_attn<<<640, 256, 0, stream>>>(qh, kh, vT, xpos, xneg);
  k_nag<<<2560, 256, 0, stream>>>(xpos, xneg, X);
  k_gemm_bt<<<dim3(20, 16), 256, 0, stream>>>(X, wB + 12582912, (float*)d_out, 2048, 2048);
}